// Round 10
// baseline (2900.888 us; speedup 1.0000x reference)
//
#include <hip/hip_runtime.h>
#include <hip/hip_bf16.h>

#define NSTEPS 100
#define DT (1.0f / 100.0f)
#define TSCALE 2.885390081777927f   // 2*log2(e): folded into W1,W2,b1,b2

typedef __attribute__((ext_vector_type(8))) short short8;     // 8 bf16 (32x32x16 A/B frag)
typedef __attribute__((ext_vector_type(16))) float float16;   // 32x32 C/D frag

__device__ __forceinline__ unsigned short f2bf(float f) {
  union { float f; unsigned int u; } v; v.f = f;
  unsigned int u = v.u;
  return (unsigned short)((u + 0x7fffu + ((u >> 16) & 1u)) >> 16);  // RNE
}
__device__ __forceinline__ unsigned int pk2(float a, float b) {
  __hip_bfloat162 h = __float22bfloat162_rn(make_float2(a, b));
  union { __hip_bfloat162 h; unsigned int u; } v; v.h = h;
  return v.u;
}
__device__ __forceinline__ float u2f(unsigned int u) {
  union { unsigned int u; float f; } v; v.u = u; return v.f;
}
// tanh with input pre-scaled by 2*log2(e): tanh = 1 - 2/(2^y + 1)
__device__ __forceinline__ float tanh_pre(float y) {
  float e = __builtin_amdgcn_exp2f(y);
  return 1.0f - 2.0f * __builtin_amdgcn_rcpf(e + 1.0f);
}

// Repack W (K x N row-major fp32) into 32x32x16 A-frag-major bf16 (A-frag of W^T):
// element ((s*NT + mt)*64 + l)*8 + j holds W[k = s*16 + 8*(l>>5) + j][n = mt*32 + (l&31)].
// W1/W2 pre-scaled by TSCALE.
__global__ void prep_weights(const float* __restrict__ W1,
                             const float* __restrict__ W2,
                             const float* __restrict__ W3,
                             unsigned short* __restrict__ ws) {
  int e = blockIdx.x * 256 + threadIdx.x;  // 98304 total
  const float* src; int N, NT, el, base; float sc;
  if (e < 16384)      { src = W1; N = 256; NT = 8; base = 0;     el = e;         sc = TSCALE; }
  else if (e < 81920) { src = W2; N = 256; NT = 8; base = 16384; el = e - 16384; sc = TSCALE; }
  else                { src = W3; N = 64;  NT = 2; base = 81920; el = e - 81920; sc = 1.0f; }
  int j = el & 7;
  int l = (el >> 3) & 63;
  int rem = el >> 9;
  int mt = rem % NT;
  int s  = rem / NT;
  int k = s * 16 + ((l >> 5) << 3) + j;
  int n = mt * 32 + (l & 31);
  ws[base + el] = f2bf(src[k * N + n] * sc);
}

// 32x32x16 version, single-group (R5 structure). Transposed frame:
// M = features (weights = A operand), N = batch (64 rows/block = 2 N32-tiles,
// activations = B operand, frag-major LDS: (n,k) at ((nt*NS+s)*64+ld)*8+j,
// ld=(n&31)+32*((k>>3)&1), s=k>>4, j=k&7 -> B reads are wave-contiguous b128,
// epilogue uint2 writes hit all 32 banks exactly 4x (conflict-free).
// W1/W2 register A-frags; W3 in LDS; biases packed bf16.
// Wave w: L1/L2 M-tile w; waves 0-3: L3 tile (mt=w&1, ntw=w>>1) + RK4 state.
__global__ __launch_bounds__(512, 2)
void cnf_kernel(const float* __restrict__ z0,
                const float* __restrict__ b1,
                const float* __restrict__ b2,
                const float* __restrict__ b3,
                const unsigned short* __restrict__ wsAll,
                float* __restrict__ out) {
  extern __shared__ unsigned short smem[];   // 73728 B
  unsigned short* Zbuf = smem;               //  8192 B (2 nt * 4 s * 512)
  unsigned short* Hbuf = smem + 4096;        // 32768 B (2 nt * 16 s * 512)
  unsigned short* LW3  = smem + 20480;       // 32768 B (16 s * 2 mt * 512)

  const int tid  = threadIdx.x;
  const int w    = tid >> 6;
  const int lane = tid & 63;
  const int i31  = lane & 31;
  const int h    = lane >> 5;
  const int grow = blockIdx.x * 64;
  const int mt   = w & 1;          // L3 M-tile (waves 0-3)
  const int ntw  = (w >> 1) & 1;   // L3 N-tile (waves 0-3)

  const unsigned short* wsW1 = wsAll;
  const unsigned short* wsW2 = wsAll + 16384;
  const unsigned short* wsW3 = wsAll + 81920;

  // ---- W3 -> LDS (once): 2048 uint4 over 512 threads ----
  {
    const uint4* s3 = (const uint4*)wsW3;
    uint4* d3 = (uint4*)LW3;
#pragma unroll
    for (int i = 0; i < 4; ++i) d3[tid + 512 * i] = s3[tid + 512 * i];
  }

  // ---- register-resident W1 (16) + W2 (64) A-frags ----
  short8 w1f[4], w2f[16];
#pragma unroll
  for (int s = 0; s < 4; ++s)
    w1f[s] = *(const short8*)&wsW1[(s * 8 + w) * 512 + lane * 8];
#pragma unroll
  for (int s = 0; s < 16; ++s)
    w2f[s] = *(const short8*)&wsW2[(s * 8 + w) * 512 + lane * 8];

  // ---- biases packed bf16 (24 regs): index r=4g+rr -> k = base + 8g + 4h + rr ----
  unsigned int b1p[4][2], b2p[4][2], b3p[4][2];
#pragma unroll
  for (int g = 0; g < 4; ++g) {
    const int k0 = w * 32 + 8 * g + 4 * h;
    b1p[g][0] = pk2(b1[k0] * TSCALE, b1[k0 + 1] * TSCALE);
    b1p[g][1] = pk2(b1[k0 + 2] * TSCALE, b1[k0 + 3] * TSCALE);
    b2p[g][0] = pk2(b2[k0] * TSCALE, b2[k0 + 1] * TSCALE);
    b2p[g][1] = pk2(b2[k0 + 2] * TSCALE, b2[k0 + 3] * TSCALE);
    const int k3 = mt * 32 + 8 * g + 4 * h;   // in-bounds for all waves; used by 0-3
    b3p[g][0] = pk2(b3[k3], b3[k3 + 1]);
    b3p[g][1] = pk2(b3[k3 + 2], b3[k3 + 3]);
  }

  // ---- RK4 state (waves 0-3): 16 elements, C-layout rows ----
  float z[16], zacc[16];
  if (w < 4) {
#pragma unroll
    for (int g = 0; g < 4; ++g) {
      float4 v = *(const float4*)&z0[(grow + ntw * 32 + i31) * 64 + mt * 32 + 8 * g + 4 * h];
      z[4 * g + 0] = v.x; z[4 * g + 1] = v.y; z[4 * g + 2] = v.z; z[4 * g + 3] = v.w;
#pragma unroll
      for (int r = 0; r < 4; ++r) zacc[4 * g + r] = 0.f;
      uint2 p; p.x = pk2(v.x, v.y); p.y = pk2(v.z, v.w);
      *(uint2*)&Zbuf[((ntw * 4 + 2 * mt + (g >> 1)) * 64 + i31 + 32 * (g & 1)) * 8 + 4 * h] = p;
    }
  }

  const float DT6 = DT / 6.0f, DT3 = DT / 3.0f, DTH = 0.5f * DT;
  const int rb = lane * 8;   // frag read base; frag index adds *512

  auto initAcc16 = [&](unsigned int (&bp)[4][2]) -> float16 {
    float16 a;
#pragma unroll
    for (int g = 0; g < 4; ++g) {
      a[4 * g + 0] = u2f(bp[g][0] << 16);
      a[4 * g + 1] = u2f(bp[g][0] & 0xffff0000u);
      a[4 * g + 2] = u2f(bp[g][1] << 16);
      a[4 * g + 3] = u2f(bp[g][1] & 0xffff0000u);
    }
    return a;
  };

#pragma unroll 1
  for (int it = 0; it < NSTEPS * 4; ++it) {
    const int st = it & 3;
    __syncthreads();  // B1: Zbuf ready; prev P3 Hbuf reads done

    // ---- Layer 1: K=64 (4 k-steps), acc init = b1 ----
    float16 acc[2];
    acc[0] = initAcc16(b1p);
    acc[1] = acc[0];
#pragma unroll
    for (int s = 0; s < 4; ++s)
#pragma unroll
      for (int nt = 0; nt < 2; ++nt) {
        short8 bz = *(const short8*)&Zbuf[rb + (nt * 4 + s) * 512];
        acc[nt] = __builtin_amdgcn_mfma_f32_32x32x16_bf16(w1f[s], bz, acc[nt], 0, 0, 0);
      }
    // E1 -> Hbuf
#pragma unroll
    for (int nt = 0; nt < 2; ++nt)
#pragma unroll
      for (int g = 0; g < 4; ++g) {
        uint2 p;
        p.x = pk2(tanh_pre(acc[nt][4 * g + 0]), tanh_pre(acc[nt][4 * g + 1]));
        p.y = pk2(tanh_pre(acc[nt][4 * g + 2]), tanh_pre(acc[nt][4 * g + 3]));
        *(uint2*)&Hbuf[((nt * 16 + 2 * w + (g >> 1)) * 64 + i31 + 32 * (g & 1)) * 8 + 4 * h] = p;
      }
    __syncthreads();  // B2: H1 visible

    // ---- Layer 2: K=256 (16 k-steps), acc init = b2 ----
    float16 acc2[2];
    acc2[0] = initAcc16(b2p);
    acc2[1] = acc2[0];
#pragma unroll
    for (int s = 0; s < 16; ++s)
#pragma unroll
      for (int nt = 0; nt < 2; ++nt) {
        short8 bh = *(const short8*)&Hbuf[rb + (nt * 16 + s) * 512];
        acc2[nt] = __builtin_amdgcn_mfma_f32_32x32x16_bf16(w2f[s], bh, acc2[nt], 0, 0, 0);
      }
    __syncthreads();  // B3: H1 reads done -> Hbuf may be overwritten

    // E2 -> Hbuf
#pragma unroll
    for (int nt = 0; nt < 2; ++nt)
#pragma unroll
      for (int g = 0; g < 4; ++g) {
        uint2 p;
        p.x = pk2(tanh_pre(acc2[nt][4 * g + 0]), tanh_pre(acc2[nt][4 * g + 1]));
        p.y = pk2(tanh_pre(acc2[nt][4 * g + 2]), tanh_pre(acc2[nt][4 * g + 3]));
        *(uint2*)&Hbuf[((nt * 16 + 2 * w + (g >> 1)) * 64 + i31 + 32 * (g & 1)) * 8 + 4 * h] = p;
      }
    __syncthreads();  // B4: H2 visible

    // ---- Layer 3 + RK4 (waves 0-3) ----
    if (w < 4) {
      float16 a3 = initAcc16(b3p);
#pragma unroll
      for (int s = 0; s < 16; ++s) {
        short8 wf = *(const short8*)&LW3[rb + (s * 2 + mt) * 512];
        short8 bh = *(const short8*)&Hbuf[rb + (ntw * 16 + s) * 512];
        a3 = __builtin_amdgcn_mfma_f32_32x32x16_bf16(wf, bh, a3, 0, 0, 0);
      }
      const float wsum  = (st == 0 || st == 3) ? DT6 : DT3;
      const float cst   = (st == 2) ? DT : DTH;
      const bool  last  = (st == 3);
      const bool  first = (st == 0);
#pragma unroll
      for (int g = 0; g < 4; ++g) {
        float stg[4];
#pragma unroll
        for (int r = 0; r < 4; ++r) {
          const int i = 4 * g + r;
          float k = a3[i];
          float za = first ? z[i] : zacc[i];
          za += wsum * k;
          zacc[i] = za;
          if (last) { z[i] = za; stg[r] = za; }
          else      { stg[r] = z[i] + cst * k; }
        }
        uint2 p; p.x = pk2(stg[0], stg[1]); p.y = pk2(stg[2], stg[3]);
        *(uint2*)&Zbuf[((ntw * 4 + 2 * mt + (g >> 1)) * 64 + i31 + 32 * (g & 1)) * 8 + 4 * h] = p;
      }
    }
  }

  // ---- final store (waves 0-3) ----
  if (w < 4) {
#pragma unroll
    for (int g = 0; g < 4; ++g) {
      float4 v;
      v.x = z[4 * g + 0]; v.y = z[4 * g + 1]; v.z = z[4 * g + 2]; v.w = z[4 * g + 3];
      *(float4*)&out[(grow + ntw * 32 + i31) * 64 + mt * 32 + 8 * g + 4 * h] = v;
    }
  }
}

extern "C" void kernel_launch(void* const* d_in, const int* in_sizes, int n_in,
                              void* d_out, int out_size, void* d_ws, size_t ws_size,
                              hipStream_t stream) {
  const float* z0 = (const float*)d_in[0];
  const float* W1 = (const float*)d_in[1];
  const float* b1 = (const float*)d_in[2];
  const float* W2 = (const float*)d_in[3];
  const float* b2 = (const float*)d_in[4];
  const float* W3 = (const float*)d_in[5];
  const float* b3 = (const float*)d_in[6];
  unsigned short* ws = (unsigned short*)d_ws;  // 98304 bf16 = 196608 B

  prep_weights<<<384, 256, 0, stream>>>(W1, W2, W3, ws);
  (void)hipFuncSetAttribute((const void*)cnf_kernel,
                            hipFuncAttributeMaxDynamicSharedMemorySize, 73728);
  cnf_kernel<<<512, 512, 73728, stream>>>(z0, b1, b2, b3, ws, (float*)d_out);
}